// Round 1
// baseline (376.812 us; speedup 1.0000x reference)
//
#include <hip/hip_runtime.h>

// LSTM cell, B=131072, IN=H=128, fp32 in/out.
// Strategy: single fused GEMM [x|h_prev](131072x256) @ Bprep(256x512) in bf16 MFMA,
// gate-interleaved weight column order so each lane owns all 4 gates of its h-col,
// fp32 elementwise epilogue in-register, direct coalesced stores.

#define B_ROWS 131072
#define HDIM 128
#define KDIM 256
#define BM 32
#define LDA 264   // 256 + 8 pad (bf16 elems): row stride 528 B == 4 banks -> 2-way only

typedef __attribute__((ext_vector_type(4))) float f32x4;
typedef __attribute__((ext_vector_type(8))) short s16x8;

__device__ inline unsigned short f2bf(float f) {
    unsigned int u = __float_as_uint(f);
    u += 0x7fffu + ((u >> 16) & 1u);   // round-to-nearest-even (inputs finite)
    return (unsigned short)(u >> 16);
}

__device__ inline float frcp(float x) { return __builtin_amdgcn_rcpf(x); }
__device__ inline float fsigmoid(float x) { return frcp(1.0f + __expf(-x)); }
__device__ inline float ftanh(float x) { return 1.0f - 2.0f * frcp(__expf(2.0f * x) + 1.0f); }

// Bprep element layout: addr = c*256 + k (bf16), where gate-col c encodes:
//   w = c>>6 (wave), ni = (c>>4)&3 (gate), t = c&15 ; h-col j = w*16 + t
// value = k<128 ? W_gate[k][j] : U_gate[k-128][j]
__global__ void prep_weights(const float* __restrict__ Wi, const float* __restrict__ Ui,
                             const float* __restrict__ Wf, const float* __restrict__ Uf,
                             const float* __restrict__ Wg, const float* __restrict__ Ug,
                             const float* __restrict__ Wo, const float* __restrict__ Uo,
                             unsigned short* __restrict__ Bp) {
    int idx = blockIdx.x * 256 + threadIdx.x;   // 0..131071
    int c = idx >> 8;
    int k = idx & 255;
    int w = c >> 6;
    int gate = (c >> 4) & 3;
    int t = c & 15;
    int j = w * 16 + t;
    const float* Wp = gate == 0 ? Wi : gate == 1 ? Wf : gate == 2 ? Wg : Wo;
    const float* Up = gate == 0 ? Ui : gate == 1 ? Uf : gate == 2 ? Ug : Uo;
    float v = (k < 128) ? Wp[k * HDIM + j] : Up[(k - 128) * HDIM + j];
    Bp[idx] = f2bf(v);
}

__global__ __launch_bounds__(512, 4) void lstm_main(
    const float* __restrict__ x, const float* __restrict__ h_prev,
    const float* __restrict__ c_prev,
    const unsigned short* __restrict__ Bp,
    const float* __restrict__ bi, const float* __restrict__ bf_,
    const float* __restrict__ bg, const float* __restrict__ bo,
    float* __restrict__ out)
{
    __shared__ unsigned short At[BM * LDA];

    const int tid = threadIdx.x;
    const int m0 = blockIdx.x * BM;

    // ---- Stage A tile (32 rows x 256 K) fp32 -> bf16 into LDS, coalesced float4 loads
    #pragma unroll
    for (int it = 0; it < 4; ++it) {
        int fi = tid + it * 512;               // 0..2047 float4s
        int r = fi >> 6;                       // row 0..31
        int c4 = fi & 63;                      // float4 within row
        const float* src = (c4 < 32) ? (x + (size_t)(m0 + r) * HDIM + c4 * 4)
                                     : (h_prev + (size_t)(m0 + r) * HDIM + (c4 - 32) * 4);
        float4 v = *(const float4*)src;
        ushort4 p;
        p.x = f2bf(v.x); p.y = f2bf(v.y); p.z = f2bf(v.z); p.w = f2bf(v.w);
        *(ushort4*)&At[r * LDA + c4 * 4] = p;
    }
    __syncthreads();

    const int wave = tid >> 6;
    const int lane = tid & 63;
    const int t16 = lane & 15;
    const int q = lane >> 4;

    f32x4 acc[2][4];
    const f32x4 zero = {0.0f, 0.0f, 0.0f, 0.0f};
    #pragma unroll
    for (int mi = 0; mi < 2; ++mi)
        #pragma unroll
        for (int ni = 0; ni < 4; ++ni)
            acc[mi][ni] = zero;

    // B fragment base: col = wave*64 + ni*16 + t16, elem = col*256 + kc*32 + q*8
    const unsigned short* bbase = Bp + (size_t)(wave * 64 + t16) * KDIM + q * 8;

    // ---- K loop: 8 steps of K=32, no barriers (B from L2-resident global)
    #pragma unroll
    for (int kc = 0; kc < 8; ++kc) {
        const int k = kc * 32 + q * 8;
        s16x8 a[2], b[4];
        #pragma unroll
        for (int mi = 0; mi < 2; ++mi)
            a[mi] = *(const s16x8*)&At[(mi * 16 + t16) * LDA + k];
        #pragma unroll
        for (int ni = 0; ni < 4; ++ni)
            b[ni] = *(const s16x8*)(bbase + ni * 16 * KDIM + kc * 32);
        #pragma unroll
        for (int mi = 0; mi < 2; ++mi)
            #pragma unroll
            for (int ni = 0; ni < 4; ++ni)
                acc[mi][ni] = __builtin_amdgcn_mfma_f32_16x16x32_bf16(a[mi], b[ni], acc[mi][ni], 0, 0, 0);
    }

    // ---- Epilogue: lane owns h-col j, gates i/f/g/o in acc[mi][0..3]; all fp32
    const int j = wave * 16 + t16;
    const float vbi = bi[j], vbf = bf_[j], vbg = bg[j], vbo = bo[j];
    float* hout = out;
    float* cout = out + (size_t)B_ROWS * HDIM;

    #pragma unroll
    for (int mi = 0; mi < 2; ++mi) {
        #pragma unroll
        for (int r = 0; r < 4; ++r) {
            int row = m0 + mi * 16 + q * 4 + r;   // C/D layout: col=lane&15, row=(lane>>4)*4+reg
            size_t off = (size_t)row * HDIM + j;
            float cp = c_prev[off];
            float ig = fsigmoid(acc[mi][0][r] + vbi);
            float fg = fsigmoid(acc[mi][1][r] + vbf);
            float cc = ftanh(acc[mi][2][r] + vbg);
            float og = fsigmoid(acc[mi][3][r] + vbo);
            float c = fg * cp + ig * cc;
            float h = og * ftanh(c);
            hout[off] = h;
            cout[off] = c;
        }
    }
}

extern "C" void kernel_launch(void* const* d_in, const int* in_sizes, int n_in,
                              void* d_out, int out_size, void* d_ws, size_t ws_size,
                              hipStream_t stream) {
    const float* x      = (const float*)d_in[0];
    const float* h_prev = (const float*)d_in[1];
    const float* c_prev = (const float*)d_in[2];
    const float* Wi = (const float*)d_in[3];
    const float* Ui = (const float*)d_in[4];
    const float* bi = (const float*)d_in[5];
    const float* Wf = (const float*)d_in[6];
    const float* Uf = (const float*)d_in[7];
    const float* bf = (const float*)d_in[8];
    const float* Wg = (const float*)d_in[9];
    const float* Ug = (const float*)d_in[10];
    const float* bg = (const float*)d_in[11];
    const float* Wo = (const float*)d_in[12];
    const float* Uo = (const float*)d_in[13];
    const float* bo = (const float*)d_in[14];

    unsigned short* Bp = (unsigned short*)d_ws;   // 256 KB bf16 prepped weights

    prep_weights<<<512, 256, 0, stream>>>(Wi, Ui, Wf, Uf, Wg, Ug, Wo, Uo, Bp);
    lstm_main<<<B_ROWS / BM, 512, 0, stream>>>(x, h_prev, c_prev, Bp, bi, bf, bg, bo, (float*)d_out);
}

// Round 2
// 347.723 us; speedup vs baseline: 1.0837x; 1.0837x over previous
//
#include <hip/hip_runtime.h>

// LSTM cell, B=131072, IN=H=128, fp32 in/out.
// R2: fused GEMM [x|h](131072x256) @ Bprep(256x512) bf16 MFMA.
//   - B pre-transformed to per-(wave,kc,gate) fragment order -> every b-load is
//     64 lanes x 16B fully contiguous (was 16 scattered 512B-strided lines).
//   - A staged to LDS in fragment order (contiguous ds_read_b128, no pad games).
//   - BM=64 (halves B L2 re-read traffic vs BM=32), acc[4][4] per lane.

#define B_ROWS 131072
#define HDIM 128
#define KDIM 256
#define BM 64

typedef __attribute__((ext_vector_type(4))) float f32x4;
typedef __attribute__((ext_vector_type(8))) short s16x8;

__device__ inline unsigned short f2bf(float f) {
    unsigned int u = __float_as_uint(f);
    u += 0x7fffu + ((u >> 16) & 1u);   // RNE (inputs finite)
    return (unsigned short)(u >> 16);
}

__device__ inline float frcp(float x) { return __builtin_amdgcn_rcpf(x); }
__device__ inline float fsigmoid(float x) { return frcp(1.0f + __expf(-x)); }
__device__ inline float ftanh(float x) { return 1.0f - 2.0f * frcp(__expf(2.0f * x) + 1.0f); }

// Bp layout (ushort idx): (((w*8 + kc)*4 + ni)*512) + t16*32 + q*8 + e
//   w=0..7 (wave), kc=0..7 (K step of 32), ni=0..3 (gate i/f/g/o), t16=0..15, q=0..3, e=0..7
//   h-col j = w*16 + t16 ; k = kc*32 + q*8 + e ; value = k<128 ? W[k][j] : U[k-128][j]
__global__ void prep_weights(const float* __restrict__ Wi, const float* __restrict__ Ui,
                             const float* __restrict__ Wf, const float* __restrict__ Uf,
                             const float* __restrict__ Wg, const float* __restrict__ Ug,
                             const float* __restrict__ Wo, const float* __restrict__ Uo,
                             unsigned short* __restrict__ Bp) {
    int idx = blockIdx.x * 256 + threadIdx.x;   // 0..131071
    int e   = idx & 7;
    int q   = (idx >> 3) & 3;
    int t16 = (idx >> 5) & 15;
    int ni  = (idx >> 9) & 3;
    int kc  = (idx >> 11) & 7;
    int w   = idx >> 14;
    int j = w * 16 + t16;
    int k = kc * 32 + q * 8 + e;
    const float* Wp = ni == 0 ? Wi : ni == 1 ? Wf : ni == 2 ? Wg : Wo;
    const float* Up = ni == 0 ? Ui : ni == 1 ? Uf : ni == 2 ? Ug : Uo;
    float v = (k < 128) ? Wp[k * HDIM + j] : Up[(k - 128) * HDIM + j];
    Bp[idx] = f2bf(v);
}

__global__ __launch_bounds__(512, 4) void lstm_main(
    const float* __restrict__ x, const float* __restrict__ h_prev,
    const float* __restrict__ c_prev,
    const unsigned short* __restrict__ Bp,
    const float* __restrict__ bi, const float* __restrict__ bf_,
    const float* __restrict__ bg, const float* __restrict__ bo,
    float* __restrict__ out)
{
    // A tile in fragment order: [mi(4)][kc(8)][t16(16)][q(4)][e(8)] ushorts = 32 KB
    __shared__ unsigned short As[4 * 8 * 512];

    const int tid = threadIdx.x;
    const int m0 = blockIdx.x * BM;

    // ---- Stage A (64 rows x 256 K) fp32 -> bf16 into frag-order LDS
    #pragma unroll
    for (int it = 0; it < 8; ++it) {
        int fi = it * 512 + tid;               // 0..4095 float4s
        int r  = fi >> 6;                      // row 0..63
        int c4 = fi & 63;                      // float4 within row (k0 = c4*4)
        int k0 = c4 * 4;
        const float* src = (k0 < 128) ? (x + (size_t)(m0 + r) * HDIM + k0)
                                      : (h_prev + (size_t)(m0 + r) * HDIM + (k0 - 128));
        float4 v = *(const float4*)src;
        ushort4 p;
        p.x = f2bf(v.x); p.y = f2bf(v.y); p.z = f2bf(v.z); p.w = f2bf(v.w);
        int mi = r >> 4, t16r = r & 15;
        int kc = k0 >> 5, qq = (k0 >> 3) & 3, e0 = k0 & 7;
        *(ushort4*)&As[((mi * 8 + kc) * 16 + t16r) * 32 + qq * 8 + e0] = p;
    }
    __syncthreads();

    const int wave = tid >> 6;
    const int lane = tid & 63;
    const int t16 = lane & 15;
    const int q = lane >> 4;
    const int lane_off = t16 * 32 + q * 8;     // ushort offset within a 512-ushort frag

    f32x4 acc[4][4];
    const f32x4 zero = {0.0f, 0.0f, 0.0f, 0.0f};
    #pragma unroll
    for (int mi = 0; mi < 4; ++mi)
        #pragma unroll
        for (int ni = 0; ni < 4; ++ni)
            acc[mi][ni] = zero;

    const unsigned short* bbase = Bp + (size_t)(wave * 8) * 2048 + lane_off;

    // ---- K loop: 8 steps of K=32, no barriers; b-loads contiguous 1KB/instr
    #pragma unroll
    for (int kc = 0; kc < 8; ++kc) {
        s16x8 a[4], b[4];
        #pragma unroll
        for (int ni = 0; ni < 4; ++ni)
            b[ni] = *(const s16x8*)(bbase + kc * 2048 + ni * 512);
        #pragma unroll
        for (int mi = 0; mi < 4; ++mi)
            a[mi] = *(const s16x8*)&As[(mi * 8 + kc) * 512 + lane_off];
        #pragma unroll
        for (int mi = 0; mi < 4; ++mi)
            #pragma unroll
            for (int ni = 0; ni < 4; ++ni)
                acc[mi][ni] = __builtin_amdgcn_mfma_f32_16x16x32_bf16(a[mi], b[ni], acc[mi][ni], 0, 0, 0);
    }

    // ---- Epilogue: lane owns h-col j; gates i/f/g/o in acc[mi][0..3]; fp32 math
    const int j = wave * 16 + t16;
    const float vbi = bi[j], vbf = bf_[j], vbg = bg[j], vbo = bo[j];
    float* hout = out;
    float* cout = out + (size_t)B_ROWS * HDIM;

    float cp[4][4];
    #pragma unroll
    for (int mi = 0; mi < 4; ++mi)
        #pragma unroll
        for (int r = 0; r < 4; ++r)
            cp[mi][r] = c_prev[(size_t)(m0 + mi * 16 + q * 4 + r) * HDIM + j];

    #pragma unroll
    for (int mi = 0; mi < 4; ++mi) {
        #pragma unroll
        for (int r = 0; r < 4; ++r) {
            int row = m0 + mi * 16 + q * 4 + r;   // C/D: col=lane&15, row=(lane>>4)*4+reg
            size_t off = (size_t)row * HDIM + j;
            float ig = fsigmoid(acc[mi][0][r] + vbi);
            float fg = fsigmoid(acc[mi][1][r] + vbf);
            float cc = ftanh(acc[mi][2][r] + vbg);
            float og = fsigmoid(acc[mi][3][r] + vbo);
            float c = fg * cp[mi][r] + ig * cc;
            float h = og * ftanh(c);
            hout[off] = h;
            cout[off] = c;
        }
    }
}

extern "C" void kernel_launch(void* const* d_in, const int* in_sizes, int n_in,
                              void* d_out, int out_size, void* d_ws, size_t ws_size,
                              hipStream_t stream) {
    const float* x      = (const float*)d_in[0];
    const float* h_prev = (const float*)d_in[1];
    const float* c_prev = (const float*)d_in[2];
    const float* Wi = (const float*)d_in[3];
    const float* Ui = (const float*)d_in[4];
    const float* bi = (const float*)d_in[5];
    const float* Wf = (const float*)d_in[6];
    const float* Uf = (const float*)d_in[7];
    const float* bf = (const float*)d_in[8];
    const float* Wg = (const float*)d_in[9];
    const float* Ug = (const float*)d_in[10];
    const float* bg = (const float*)d_in[11];
    const float* Wo = (const float*)d_in[12];
    const float* Uo = (const float*)d_in[13];
    const float* bo = (const float*)d_in[14];

    unsigned short* Bp = (unsigned short*)d_ws;   // 256 KB bf16 prepped weights

    prep_weights<<<512, 256, 0, stream>>>(Wi, Ui, Wf, Uf, Wg, Ug, Wo, Uo, Bp);
    lstm_main<<<B_ROWS / BM, 512, 0, stream>>>(x, h_prev, c_prev, Bp, bi, bf, bg, bo, (float*)d_out);
}

// Round 3
// 328.781 us; speedup vs baseline: 1.1461x; 1.0576x over previous
//
#include <hip/hip_runtime.h>

// LSTM cell, B=131072, IN=H=128, fp32 in/out.
// R3: fused GEMM [x|h](131072x256) @ Bprep(256x512) bf16 MFMA (unchanged core)
//   + LDS epilogue transpose: h/c computed in MFMA layout, routed through
//     padded LDS tiles (stride 132 -> 2-way bank aliasing only), stored with
//     fully coalesced float4 (whole 128-B lines). c_prev loaded coalesced too.
//   R2 showed WRITE_SIZE 226 MB vs 134 ideal from scattered 64-B half-line stores.

#define B_ROWS 131072
#define HDIM 128
#define KDIM 256
#define BM 64
#define LDT 132   // padded LDS tile row stride (floats); 132%32=4 -> 2-way aliasing

typedef __attribute__((ext_vector_type(4))) float f32x4;
typedef __attribute__((ext_vector_type(8))) short s16x8;

__device__ inline unsigned short f2bf(float f) {
    unsigned int u = __float_as_uint(f);
    u += 0x7fffu + ((u >> 16) & 1u);   // RNE (inputs finite)
    return (unsigned short)(u >> 16);
}

__device__ inline float frcp(float x) { return __builtin_amdgcn_rcpf(x); }
__device__ inline float fsigmoid(float x) { return frcp(1.0f + __expf(-x)); }
__device__ inline float ftanh(float x) { return 1.0f - 2.0f * frcp(__expf(2.0f * x) + 1.0f); }

// Bp layout (ushort idx): (((w*8 + kc)*4 + ni)*512) + t16*32 + q*8 + e
__global__ void prep_weights(const float* __restrict__ Wi, const float* __restrict__ Ui,
                             const float* __restrict__ Wf, const float* __restrict__ Uf,
                             const float* __restrict__ Wg, const float* __restrict__ Ug,
                             const float* __restrict__ Wo, const float* __restrict__ Uo,
                             unsigned short* __restrict__ Bp) {
    int idx = blockIdx.x * 256 + threadIdx.x;   // 0..131071
    int e   = idx & 7;
    int q   = (idx >> 3) & 3;
    int t16 = (idx >> 5) & 15;
    int ni  = (idx >> 9) & 3;
    int kc  = (idx >> 11) & 7;
    int w   = idx >> 14;
    int j = w * 16 + t16;
    int k = kc * 32 + q * 8 + e;
    const float* Wp = ni == 0 ? Wi : ni == 1 ? Wf : ni == 2 ? Wg : Wo;
    const float* Up = ni == 0 ? Ui : ni == 1 ? Uf : ni == 2 ? Ug : Uo;
    float v = (k < 128) ? Wp[k * HDIM + j] : Up[(k - 128) * HDIM + j];
    Bp[idx] = f2bf(v);
}

__global__ __launch_bounds__(512, 4) void lstm_main(
    const float* __restrict__ x, const float* __restrict__ h_prev,
    const float* __restrict__ c_prev,
    const unsigned short* __restrict__ Bp,
    const float* __restrict__ bi, const float* __restrict__ bf_,
    const float* __restrict__ bg, const float* __restrict__ bo,
    float* __restrict__ out)
{
    // 2 padded fp32 tiles (64 x 132) = 67584 B. First 32 KB of hbuf doubles as
    // the bf16 A-staging buffer during the GEMM phase.
    __shared__ float smem[2 * BM * LDT];
    float* hbuf = smem;
    float* cbuf = smem + BM * LDT;
    unsigned short* As = (unsigned short*)smem;   // [mi(4)][kc(8)][t16(16)][q(4)][e(8)] = 32 KB

    const int tid = threadIdx.x;
    const int m0 = blockIdx.x * BM;

    // ---- c_prev: coalesced float4 loads (issue early for latency overlap)
    float4 cpv[4];
    #pragma unroll
    for (int it = 0; it < 4; ++it) {
        int f = it * 512 + tid;
        int r = f >> 5, c4 = f & 31;
        cpv[it] = *(const float4*)(c_prev + (size_t)(m0 + r) * HDIM + c4 * 4);
    }

    // ---- Stage A (64 rows x 256 K) fp32 -> bf16 into frag-order LDS
    #pragma unroll
    for (int it = 0; it < 8; ++it) {
        int fi = it * 512 + tid;               // 0..4095 float4s
        int r  = fi >> 6;                      // row 0..63
        int c4 = fi & 63;
        int k0 = c4 * 4;
        const float* src = (k0 < 128) ? (x + (size_t)(m0 + r) * HDIM + k0)
                                      : (h_prev + (size_t)(m0 + r) * HDIM + (k0 - 128));
        float4 v = *(const float4*)src;
        ushort4 p;
        p.x = f2bf(v.x); p.y = f2bf(v.y); p.z = f2bf(v.z); p.w = f2bf(v.w);
        int mi = r >> 4, t16r = r & 15;
        int kc = k0 >> 5, qq = (k0 >> 3) & 3, e0 = k0 & 7;
        *(ushort4*)&As[((mi * 8 + kc) * 16 + t16r) * 32 + qq * 8 + e0] = p;
    }

    // ---- park c_prev tile in cbuf (separate LDS region, no hazard with As)
    #pragma unroll
    for (int it = 0; it < 4; ++it) {
        int f = it * 512 + tid;
        int r = f >> 5, c4 = f & 31;
        *(float4*)&cbuf[r * LDT + c4 * 4] = cpv[it];
    }
    __syncthreads();

    const int wave = tid >> 6;
    const int lane = tid & 63;
    const int t16 = lane & 15;
    const int q = lane >> 4;
    const int lane_off = t16 * 32 + q * 8;

    f32x4 acc[4][4];
    const f32x4 zero = {0.0f, 0.0f, 0.0f, 0.0f};
    #pragma unroll
    for (int mi = 0; mi < 4; ++mi)
        #pragma unroll
        for (int ni = 0; ni < 4; ++ni)
            acc[mi][ni] = zero;

    const unsigned short* bbase = Bp + (size_t)(wave * 8) * 2048 + lane_off;

    // ---- K loop: 8 steps of K=32, no barriers; b-loads contiguous 1KB/instr
    #pragma unroll
    for (int kc = 0; kc < 8; ++kc) {
        s16x8 a[4], b[4];
        #pragma unroll
        for (int ni = 0; ni < 4; ++ni)
            b[ni] = *(const s16x8*)(bbase + kc * 2048 + ni * 512);
        #pragma unroll
        for (int mi = 0; mi < 4; ++mi)
            a[mi] = *(const s16x8*)&As[(mi * 8 + kc) * 512 + lane_off];
        #pragma unroll
        for (int mi = 0; mi < 4; ++mi)
            #pragma unroll
            for (int ni = 0; ni < 4; ++ni)
                acc[mi][ni] = __builtin_amdgcn_mfma_f32_16x16x32_bf16(a[mi], b[ni], acc[mi][ni], 0, 0, 0);
    }
    __syncthreads();   // all As reads done (hbuf overlaps As); cbuf fully written

    // ---- Epilogue in MFMA layout: read cp from LDS, compute, write h/c to LDS
    const int j = wave * 16 + t16;
    const float vbi = bi[j], vbf = bf_[j], vbg = bg[j], vbo = bo[j];

    #pragma unroll
    for (int mi = 0; mi < 4; ++mi) {
        #pragma unroll
        for (int r = 0; r < 4; ++r) {
            int rt = mi * 16 + q * 4 + r;          // row within tile
            float cp = cbuf[rt * LDT + j];
            float ig = fsigmoid(acc[mi][0][r] + vbi);
            float fg = fsigmoid(acc[mi][1][r] + vbf);
            float cc = ftanh(acc[mi][2][r] + vbg);
            float og = fsigmoid(acc[mi][3][r] + vbo);
            float c = fg * cp + ig * cc;
            float h = og * ftanh(c);
            hbuf[rt * LDT + j] = h;
            cbuf[rt * LDT + j] = c;                // own slot: read-before-write per lane
        }
    }
    __syncthreads();

    // ---- Coalesced full-line float4 stores
    float* hout = out;
    float* cout = out + (size_t)B_ROWS * HDIM;
    #pragma unroll
    for (int it = 0; it < 4; ++it) {
        int f = it * 512 + tid;
        int r = f >> 5, c4 = f & 31;
        size_t goff = (size_t)(m0 + r) * HDIM + c4 * 4;
        *(float4*)(hout + goff) = *(const float4*)&hbuf[r * LDT + c4 * 4];
        *(float4*)(cout + goff) = *(const float4*)&cbuf[r * LDT + c4 * 4];
    }
}

extern "C" void kernel_launch(void* const* d_in, const int* in_sizes, int n_in,
                              void* d_out, int out_size, void* d_ws, size_t ws_size,
                              hipStream_t stream) {
    const float* x      = (const float*)d_in[0];
    const float* h_prev = (const float*)d_in[1];
    const float* c_prev = (const float*)d_in[2];
    const float* Wi = (const float*)d_in[3];
    const float* Ui = (const float*)d_in[4];
    const float* bi = (const float*)d_in[5];
    const float* Wf = (const float*)d_in[6];
    const float* Uf = (const float*)d_in[7];
    const float* bf = (const float*)d_in[8];
    const float* Wg = (const float*)d_in[9];
    const float* Ug = (const float*)d_in[10];
    const float* bg = (const float*)d_in[11];
    const float* Wo = (const float*)d_in[12];
    const float* Uo = (const float*)d_in[13];
    const float* bo = (const float*)d_in[14];

    unsigned short* Bp = (unsigned short*)d_ws;   // 256 KB bf16 prepped weights

    prep_weights<<<512, 256, 0, stream>>>(Wi, Ui, Wf, Uf, Wg, Ug, Wo, Uo, Bp);
    lstm_main<<<B_ROWS / BM, 512, 0, stream>>>(x, h_prev, c_prev, Bp, bi, bf, bg, bo, (float*)d_out);
}